// Round 6
// baseline (65.094 us; speedup 1.0000x reference)
//
#include <hip/hip_runtime.h>
#include <math.h>

// Problem constants (match reference)
static constexpr int   kC   = 1000;    // NUM_CLASSES
static constexpr int   kD   = 256;     // EMBED_DIM
static constexpr int   kCap = 1024;    // per-class index bin capacity
static constexpr float kMom = 0.995f;  // MOMENTUM
static constexpr float kEps = 1e-12f;  // F.normalize eps

typedef float f32x4 __attribute__((ext_vector_type(4)));

__device__ __forceinline__ f32x4 nt_load4(const float* p) {
    return __builtin_nontemporal_load((const f32x4*)p);
}

// ---- block-wide sum over 512 threads (8 waves of 64) ----
__device__ __forceinline__ float block_sum512(float v) {
    __shared__ float lds[8];
    #pragma unroll
    for (int off = 32; off > 0; off >>= 1) v += __shfl_down(v, off, 64);
    __syncthreads();                       // protect lds from prior call's reads
    if ((threadIdx.x & 63) == 0) lds[threadIdx.x >> 6] = v;
    __syncthreads();
    return lds[0] + lds[1] + lds[2] + lds[3] + lds[4] + lds[5] + lds[6] + lds[7];
}

// ---- pass 1: scatter row indices into fixed-capacity class bins ----
// 4 labels per thread via int4. Overflow (statistically never: counts ~
// Poisson(131), cap 1024) goes to a global (label,row) pair list.
__global__ void k_scatter(const int* __restrict__ labels, int n,
                          int* __restrict__ cnt, int* __restrict__ idx,
                          int* __restrict__ ovf /* [0]=count, then pairs */) {
    const int t = blockIdx.x * 256 + threadIdx.x;
    const int i0 = t * 4;
    if (i0 >= n) return;
    if (i0 + 3 < n) {
        const int4 l4 = ((const int4*)labels)[t];
        #pragma unroll
        for (int k = 0; k < 4; ++k) {
            const int lab = (&l4.x)[k];
            const int i = i0 + k;
            const int p = atomicAdd(&cnt[lab], 1);
            if (p < kCap) {
                idx[(size_t)lab * kCap + p] = i;
            } else {
                const int q = atomicAdd(&ovf[0], 1);
                ovf[1 + 2 * q] = lab; ovf[2 + 2 * q] = i;
            }
        }
    } else {
        for (int i = i0; i < n; ++i) {
            const int lab = labels[i];
            const int p = atomicAdd(&cnt[lab], 1);
            if (p < kCap) {
                idx[(size_t)lab * kCap + p] = i;
            } else {
                const int q = atomicAdd(&ovf[0], 1);
                ovf[1 + 2 * q] = lab; ovf[2 + 2 * q] = i;
            }
        }
    }
}

// ---- pass 2: per-class gather-sum + fused normalize/EMA epilogue ----
// one block (8 waves, 512 thr) per class; each row read = ONE float4/lane ->
// full 1 KB row per wave instruction. 8 rows in flight per wave.
__global__ void __launch_bounds__(512)
k_reduce(const float* __restrict__ z, const float* __restrict__ protos,
         const int* __restrict__ initialized, const int* __restrict__ cnt,
         const int* __restrict__ idx, const int* __restrict__ ovf,
         float* __restrict__ out) {
    __shared__ int   sh_idx[kCap];
    __shared__ float sh_part[8][kD];

    const int c    = blockIdx.x;
    const int tid  = threadIdx.x;
    const int wave = tid >> 6;
    const int lane = tid & 63;

    const int cntc = cnt[c];
    const int m    = min(cntc, kCap);
    const int* __restrict__ cidx = idx + (size_t)c * kCap;

    // stage the whole class's index list once (<= 4 KB)
    for (int j = tid; j < m; j += 512) sh_idx[j] = cidx[j];
    __syncthreads();

    f32x4 acc0 = {0.f, 0.f, 0.f, 0.f};
    f32x4 acc1 = {0.f, 0.f, 0.f, 0.f};

    int r = wave;
    for (; r + 56 < m; r += 64) {           // 8 independent 1KB rows in flight
        const int i0 = sh_idx[r +  0]; const int i1 = sh_idx[r +  8];
        const int i2 = sh_idx[r + 16]; const int i3 = sh_idx[r + 24];
        const int i4 = sh_idx[r + 32]; const int i5 = sh_idx[r + 40];
        const int i6 = sh_idx[r + 48]; const int i7 = sh_idx[r + 56];
        const f32x4 a0 = nt_load4(z + (size_t)i0 * kD + lane * 4);
        const f32x4 a1 = nt_load4(z + (size_t)i1 * kD + lane * 4);
        const f32x4 a2 = nt_load4(z + (size_t)i2 * kD + lane * 4);
        const f32x4 a3 = nt_load4(z + (size_t)i3 * kD + lane * 4);
        const f32x4 a4 = nt_load4(z + (size_t)i4 * kD + lane * 4);
        const f32x4 a5 = nt_load4(z + (size_t)i5 * kD + lane * 4);
        const f32x4 a6 = nt_load4(z + (size_t)i6 * kD + lane * 4);
        const f32x4 a7 = nt_load4(z + (size_t)i7 * kD + lane * 4);
        acc0 += a0 + a1;
        acc1 += a2 + a3;
        acc0 += a4 + a5;
        acc1 += a6 + a7;
    }
    for (; r < m; r += 8) {
        acc0 += nt_load4(z + (size_t)sh_idx[r] * kD + lane * 4);
    }
    acc0 += acc1;

    ((f32x4*)&sh_part[wave][lane * 4])[0] = acc0;
    __syncthreads();

    // epilogue on the first 256 threads (d = tid); all 512 join reductions
    const int d = tid;
    float sum = 0.0f;
    if (d < kD) {
        #pragma unroll
        for (int w = 0; w < 8; ++w) sum += sh_part[w][d];
        // cold path: fold in overflow rows (ovf[0]==0 in practice)
        const int novf = ovf[0];
        if (novf > 0) {
            for (int j = 0; j < novf; ++j) {
                if (ovf[1 + 2 * j] == c) sum += z[(size_t)ovf[2 + 2 * j] * kD + d];
            }
        }
    }

    const float mean   = (d < kD) ? sum / fmaxf((float)cntc, 1.0f) : 0.0f;
    const float nrm    = sqrtf(block_sum512(mean * mean));
    const float mean_n = mean / fmaxf(nrm, kEps);

    const float p    = (d < kD) ? protos[c * kD + d] : 0.0f;
    const float e    = (d < kD) ? (kMom * p + (1.0f - kMom) * mean_n) : 0.0f;
    const float nrm2 = sqrtf(block_sum512(e * e));
    const float ema  = e / fmaxf(nrm2, kEps);

    if (d < kD) {
        const float cand = (initialized[c] != 0) ? ema : mean_n;
        __builtin_nontemporal_store((cntc > 0) ? cand : p, &out[c * kD + d]);
    }
}

// ================= fallback path (tiny ws): atomics into d_out ==============
__device__ __forceinline__ float block_sum256(float v) {
    __shared__ float lds[4];
    #pragma unroll
    for (int off = 32; off > 0; off >>= 1) v += __shfl_down(v, off, 64);
    __syncthreads();
    if ((threadIdx.x & 63) == 0) lds[threadIdx.x >> 6] = v;
    __syncthreads();
    return lds[0] + lds[1] + lds[2] + lds[3];
}

__global__ void k_atomic_accum(const float* __restrict__ z,
                               const int* __restrict__ labels, int n,
                               float* __restrict__ sums, int* __restrict__ counts) {
    const int i = blockIdx.x;
    const int d = threadIdx.x;
    if (i >= n) return;
    const int lab = labels[i];
    atomicAdd(&sums[lab * kD + d], z[i * kD + d]);
    if (d == 0) atomicAdd(&counts[lab], 1);
}

__global__ void k_finalize_from_sums(const float* __restrict__ protos,
                                     const int* __restrict__ initialized,
                                     const int* __restrict__ counts,
                                     float* __restrict__ out) {
    const int c = blockIdx.x;
    const int d = threadIdx.x;
    const int cntc = counts[c];
    const float sum = out[c * kD + d];

    const float mean   = sum / fmaxf((float)cntc, 1.0f);
    const float nrm    = sqrtf(block_sum256(mean * mean));
    const float mean_n = mean / fmaxf(nrm, kEps);

    const float p    = protos[c * kD + d];
    const float e    = kMom * p + (1.0f - kMom) * mean_n;
    const float nrm2 = sqrtf(block_sum256(e * e));
    const float ema  = e / fmaxf(nrm2, kEps);

    const float cand = (initialized[c] != 0) ? ema : mean_n;
    out[c * kD + d] = (cntc > 0) ? cand : p;
}

extern "C" void kernel_launch(void* const* d_in, const int* in_sizes, int n_in,
                              void* d_out, int out_size, void* d_ws, size_t ws_size,
                              hipStream_t stream) {
    const float* z           = (const float*)d_in[0];
    const float* protos      = (const float*)d_in[1];
    const int*   initialized = (const int*)d_in[2];
    const int*   labels      = (const int*)d_in[3];
    const int n = in_sizes[3];          // N (labels count)
    float* out = (float*)d_out;

    // ws layout (4-byte units):
    //   [cnt: 1024][ovf: 8 + 2N (count + pairs)][idx: kC*kCap]
    int* ws  = (int*)d_ws;
    int* cnt = ws;                          // [1024]
    int* ovf = ws + 1024;                   // [8 + 2N]
    int* idx = ws + 1024 + 8 + 2 * n;       // [kC*kCap]
    const size_t need = (size_t)(1024 + 8 + 2 * (size_t)n + (size_t)kC * kCap)
                        * sizeof(int);

    if (ws_size >= need) {
        // zero cnt + overflow count only (4.1 KB)
        (void)hipMemsetAsync(ws, 0, (size_t)(1024 + 8) * sizeof(int), stream);
        const int threads = (n + 3) / 4;
        const int blocks = (threads + 255) / 256;
        k_scatter<<<blocks, 256, 0, stream>>>(labels, n, cnt, idx, ovf);
        k_reduce <<<kC, 512, 0, stream>>>(z, protos, initialized, cnt, idx,
                                          ovf, out);
    } else {
        // fallback: accumulate sums directly in d_out with float atomics
        int* counts = ws;               // 4 KB
        (void)hipMemsetAsync(counts, 0, kC * sizeof(int), stream);
        (void)hipMemsetAsync(out, 0, (size_t)kC * kD * sizeof(float), stream);
        k_atomic_accum<<<n, kD, 0, stream>>>(z, labels, n, out, counts);
        k_finalize_from_sums<<<kC, kD, 0, stream>>>(protos, initialized, counts, out);
    }
}